// Round 1
// 218.336 us; speedup vs baseline: 1.0093x; 1.0093x over previous
//
#include <hip/hip_runtime.h>

#define Dc 256
#define Bc 4
#define Fc 60082
#define KNc 64
#define KHc 128

// workspace layout (floats):
//   [0,256)     u  = W_proj rows . w_ff
//   [256,384)   v2 = W2 rows . w_ff
//   [384,388)   constb[b] = company_out[b] + b_fc + b_ff
//   [388]       c2 = b2 . w_ff
//   [389]       c0 = b_proj . w_ff
//   [390,646)   now_term[slot] = field_emb[now_nodes[slot]] . w_ff   (slot = b*64+k)
//   [768, 768+512*128) g[slot][c] = leaky(raw[his_nodes[slot]] @ W1 + b1)[c]
#define WS_U   0
#define WS_V2  256
#define WS_CB  384
#define WS_C2  388
#define WS_C0  389
#define WS_NT  390
#define WS_G   768

__device__ __forceinline__ float wave_reduce_sum_bfly(float v) {
    #pragma unroll
    for (int off = 32; off > 0; off >>= 1)
        v += __shfl_xor(v, off, 64);
    return v;   // all lanes hold the sum
}

// K1: all precompute. 1158 waves total:
//   [0,390)    old k_pre (u, v2, constb, c2, c0)
//   [390,646)  now_term dots (independent of everything else)
//   [646,1158) his g-vectors (raw @ W1 + b1, leaky) — only raw inputs needed
__global__ void k1(const float* __restrict__ company_emb,
                   const float* __restrict__ field_emb,
                   const float* __restrict__ raw_field_embed,
                   const float* __restrict__ comp_table,
                   const float* __restrict__ W_proj,
                   const float* __restrict__ b_proj,
                   const float* __restrict__ theta,
                   const float* __restrict__ w_ff,
                   const float* __restrict__ b_ff,
                   const float* __restrict__ w_fc,
                   const float* __restrict__ b_fc,
                   const float* __restrict__ W1,
                   const float* __restrict__ b1,
                   const float* __restrict__ W2,
                   const float* __restrict__ b2,
                   const int* __restrict__ now_nodes,
                   const int* __restrict__ his_nodes,
                   const int* __restrict__ com_id,
                   float* __restrict__ ws)
{
    int gw = (blockIdx.x * blockDim.x + threadIdx.x) >> 6;
    int lane = threadIdx.x & 63;
    const float4* wf4 = (const float4*)w_ff;

    if (gw < 390) {
        float val = 0.f, addend = 0.f;
        float* dst;
        if (gw < 256) {                       // u
            float4 a = ((const float4*)(W_proj + (size_t)gw * Dc))[lane];
            float4 b = wf4[lane];
            val = a.x*b.x + a.y*b.y + a.z*b.z + a.w*b.w;
            dst = ws + WS_U + gw;
        } else if (gw < 384) {                // v2
            int j = gw - 256;
            float4 a = ((const float4*)(W2 + (size_t)j * Dc))[lane];
            float4 b = wf4[lane];
            val = a.x*b.x + a.y*b.y + a.z*b.z + a.w*b.w;
            dst = ws + WS_V2 + j;
        } else if (gw < 388) {                // constb
            int b_ = gw - 384;
            int cid = com_id[b_];
            float th = theta[cid];
            float4 x = ((const float4*)(company_emb + (size_t)b_ * Dc))[lane];
            float4 y = ((const float4*)(comp_table + (size_t)cid * Dc))[lane];
            float4 w = ((const float4*)w_fc)[lane];
            float4 m;
            m.x = (1.f - th) * x.x + th * y.x;
            m.y = (1.f - th) * x.y + th * y.y;
            m.z = (1.f - th) * x.z + th * y.z;
            m.w = (1.f - th) * x.w + th * y.w;
            val = m.x*w.x + m.y*w.y + m.z*w.z + m.w*w.w;
            addend = b_fc[0] + b_ff[0];
            dst = ws + WS_CB + b_;
        } else if (gw == 388) {               // c2
            float4 a = ((const float4*)b2)[lane];
            float4 b = wf4[lane];
            val = a.x*b.x + a.y*b.y + a.z*b.z + a.w*b.w;
            dst = ws + WS_C2;
        } else {                              // c0
            float4 a = ((const float4*)b_proj)[lane];
            float4 b = wf4[lane];
            val = a.x*b.x + a.y*b.y + a.z*b.z + a.w*b.w;
            dst = ws + WS_C0;
        }
        val = wave_reduce_sum_bfly(val);
        if (lane == 0) *dst = val + addend;
    } else if (gw < 646) {                    // now_term[slot], slot = b*64+k
        int slot = gw - 390;
        int f = now_nodes[slot];              // (B,KN) contiguous
        float4 a = ((const float4*)(field_emb + (size_t)f * Dc))[lane];
        float4 b = wf4[lane];
        float val = a.x*b.x + a.y*b.y + a.z*b.z + a.w*b.w;
        val = wave_reduce_sum_bfly(val);
        if (lane == 0) ws[WS_NT + slot] = val;
    } else if (gw < 1158) {                   // g[slot][:], slot = b*128+k
        int slot = gw - 646;
        int f = his_nodes[slot];              // (B,KH) contiguous
        float acc0 = 0.f, acc1 = 0.f;
        const float4* raw4 = (const float4*)(raw_field_embed + (size_t)f * Dc);
        #pragma unroll 2
        for (int d4 = 0; d4 < Dc / 4; ++d4) {
            float4 r4 = raw4[d4];
            const float* base = W1 + d4 * 4 * 128;
            acc0 += r4.x * base[lane]       + r4.y * base[128 + lane]
                  + r4.z * base[256 + lane] + r4.w * base[384 + lane];
            acc1 += r4.x * base[64 + lane]       + r4.y * base[128 + 64 + lane]
                  + r4.z * base[256 + 64 + lane] + r4.w * base[384 + 64 + lane];
        }
        float g0 = acc0 + b1[lane];
        float g1 = acc1 + b1[64 + lane];
        g0 = (g0 >= 0.f) ? g0 : 0.01f * g0;
        g1 = (g1 >= 0.f) ? g1 : 0.01f * g1;
        float* gr = ws + WS_G + (size_t)slot * 128;
        gr[lane]      = g0;
        gr[64 + lane] = g1;
    }
}

#define RPW 8    // rows per wave
#define RPB 32   // rows per block (4 waves)

// K2: fused sweep + fix. Per block: build LDS mark table of which of its 32
// rows are now/his-marked per batch, then the usual 16-lane-per-row dot sweep.
// Unmarked (b,f): fast broadcast write. Marked (b,f): finish inline using the
// row sum already in registers + precomputed now_term / g from K1.
__global__ void k2(const float* __restrict__ field_table,
                   const float* __restrict__ alpha_fields,
                   const int* __restrict__ now_nodes,
                   const int* __restrict__ his_nodes,
                   const float* __restrict__ ws,
                   float* __restrict__ out)
{
    __shared__ int   mark[RPB];       // bit b: now-marked, bit 4+b: his-marked
    __shared__ short know_[RPB][Bc];
    __shared__ short khis_[RPB][Bc];

    int tid  = threadIdx.x;
    int lane = tid & 63;
    int wloc = tid >> 6;
    int f0b  = blockIdx.x * RPB;

    if (tid < RPB) mark[tid] = 0;
    __syncthreads();

    // scan the 768 node entries, 3 per thread
    #pragma unroll
    for (int e = tid; e < Bc * (KNc + KHc); e += 256) {
        int b = e / (KNc + KHc);
        int j = e - b * (KNc + KHc);
        int f, bit; short kk;
        if (j < KNc) { f = now_nodes[b * KNc + j];         bit = 1 << b;       kk = (short)j; }
        else         { f = his_nodes[b * KHc + (j - KNc)]; bit = 1 << (4 + b); kk = (short)(j - KNc); }
        int rel = f - f0b;
        if (rel >= 0 && rel < RPB) {
            atomicOr(&mark[rel], bit);
            if (j < KNc) know_[rel][b] = kk; else khis_[rel][b] = kk;
        }
    }
    __syncthreads();

    int sub = lane >> 4;      // which of the 4 rows in a pass
    int c   = lane & 15;      // column slot within the row
    const float4* u4 = (const float4*)(ws + WS_U);
    float4 ub0 = u4[c], ub1 = u4[c + 16], ub2 = u4[c + 32], ub3 = u4[c + 48];
    float c0 = ws[WS_C0];
    float cb = (c < Bc) ? ws[WS_CB + c] : 0.f;
    int fbase = f0b + wloc * RPW;

    float sums[2];
    #pragma unroll
    for (int pass = 0; pass < 2; ++pass) {
        int f = fbase + pass * 4 + sub;
        float4 a0, a1, a2, a3;
        if (f < Fc) {
            const float4* row = (const float4*)(field_table + (size_t)f * Dc);
            a0 = row[c]; a1 = row[c + 16]; a2 = row[c + 32]; a3 = row[c + 48];
        } else {
            a0 = a1 = a2 = a3 = make_float4(0.f, 0.f, 0.f, 0.f);
        }
        float acc = a0.x*ub0.x + a0.y*ub0.y + a0.z*ub0.z + a0.w*ub0.w
                  + a1.x*ub1.x + a1.y*ub1.y + a1.z*ub1.z + a1.w*ub1.w
                  + a2.x*ub2.x + a2.y*ub2.y + a2.z*ub2.z + a2.w*ub2.w
                  + a3.x*ub3.x + a3.y*ub3.y + a3.z*ub3.z + a3.w*ub3.w;
        acc += __shfl_xor(acc, 1, 64);
        acc += __shfl_xor(acc, 2, 64);
        acc += __shfl_xor(acc, 4, 64);
        acc += __shfl_xor(acc, 8, 64);
        sums[pass] = acc;     // all 16 lanes of the group hold the row sum
    }

    // fast path: write all unmarked (b,f)
    #pragma unroll
    for (int pass = 0; pass < 2; ++pass) {
        int r = pass * 4 + sub;
        int f = fbase + r;
        if (f < Fc && c < Bc) {
            int m = mark[wloc * RPW + r];
            if (!(m & (0x11 << c)))
                out[(size_t)c * Fc + f] = sums[pass] + c0 + cb;
        }
    }

    // slow path: rows with any mark (wave-uniform)
    bool any = false;
    #pragma unroll
    for (int r = 0; r < RPW; ++r) any = any || (mark[wloc * RPW + r] != 0);
    if (!any) return;

    float v2l = ws[WS_V2 + lane];
    float v2h = ws[WS_V2 + 64 + lane];
    float c2  = ws[WS_C2];
    for (int r = 0; r < RPW; ++r) {
        int m = mark[wloc * RPW + r];
        if (!m) continue;
        int f = fbase + r;
        if (f >= Fc) continue;
        float alpha = alpha_fields[f];
        float s0 = __shfl(sums[0], (r & 3) << 4, 64);
        float s1 = __shfl(sums[1], (r & 3) << 4, 64);
        float sv = ((r >> 2) ? s1 : s0) + c0;
        #pragma unroll
        for (int b = 0; b < Bc; ++b) {
            int mb = (m >> b) & 0x11;
            if (!mb) continue;
            float val = (1.f - alpha) * sv + ws[WS_CB + b];
            if (mb & 1)
                val += alpha * ws[WS_NT + b * KNc + know_[wloc * RPW + r][b]];
            if (mb & 0x10) {
                const float* gr = ws + WS_G
                                + (size_t)(b * KHc + khis_[wloc * RPW + r][b]) * 128;
                float p = gr[lane] * v2l + gr[64 + lane] * v2h;
                p = wave_reduce_sum_bfly(p);
                val += alpha * (p + c2);
            }
            if (lane == 0) out[(size_t)b * Fc + f] = val;
        }
    }
}

extern "C" void kernel_launch(void* const* d_in, const int* in_sizes, int n_in,
                              void* d_out, int out_size, void* d_ws, size_t ws_size,
                              hipStream_t stream) {
    const float* company_emb     = (const float*)d_in[0];
    const float* field_emb       = (const float*)d_in[1];
    const float* raw_field_embed = (const float*)d_in[2];
    const float* comp_table      = (const float*)d_in[3];
    const float* field_table     = (const float*)d_in[4];
    const float* W_proj          = (const float*)d_in[5];
    const float* b_proj          = (const float*)d_in[6];
    const float* theta           = (const float*)d_in[7];
    const float* alpha_fields    = (const float*)d_in[8];
    const float* w_ff            = (const float*)d_in[9];
    const float* b_ff            = (const float*)d_in[10];
    const float* w_fc            = (const float*)d_in[11];
    const float* b_fc            = (const float*)d_in[12];
    const float* W1              = (const float*)d_in[13];
    const float* b1              = (const float*)d_in[14];
    const float* W2              = (const float*)d_in[15];
    const float* b2              = (const float*)d_in[16];
    const int*   now_nodes       = (const int*)d_in[17];
    const int*   his_nodes       = (const int*)d_in[18];
    const int*   com_id          = (const int*)d_in[19];

    float* ws  = (float*)d_ws;
    float* out = (float*)d_out;

    // 1158 waves -> 290 blocks of 4 waves
    k1<<<(1158 + 3) / 4, 256, 0, stream>>>(company_emb, field_emb, raw_field_embed,
                                           comp_table, W_proj, b_proj, theta,
                                           w_ff, b_ff, w_fc, b_fc, W1, b1, W2, b2,
                                           now_nodes, his_nodes, com_id, ws);

    // one block per 32 rows
    k2<<<(Fc + RPB - 1) / RPB, 256, 0, stream>>>(field_table, alpha_fields,
                                                 now_nodes, his_nodes, ws, out);
}